// Round 10
// baseline (64.810 us; speedup 1.0000x reference)
//
#include <hip/hip_runtime.h>

#define POOL 7
#define NUM_ROIS 512
#define H_IMG 128
#define W_IMG 128
#define C_IMG 1024
#define NITEMS (NUM_ROIS * POOL)   // 3584 work items = (roi, py) rows
#define NBINS 8192                 // key = ay0*64 + roi.x  (row, col-origin)
#define IMG16_BYTES ((size_t)H_IMG * W_IMG * C_IMG * 2)   // 33,554,432

typedef float    f32x4 __attribute__((ext_vector_type(4)));
typedef _Float16 f16x8 __attribute__((ext_vector_type(8)));

// ---------------------------------------------------------------------------
// Pass 0: convert the fp32 image to fp16 in d_ws. Image is read exactly once
// per call (stays L3-resident across replays); fp16 copy (33.5MB) lives in
// L2/L3 for the gather pass. Halves gather read-bytes AND VMEM instr count.
// fp16 rounding error <= 2^-11 * |x| ~ 0.003, far under the 0.093 threshold.
// ---------------------------------------------------------------------------
__global__ __launch_bounds__(256) void convert_kernel(
    const float* __restrict__ img, _Float16* __restrict__ img16)
{
    const int n8     = (H_IMG * W_IMG * C_IMG) / 8;   // 2,097,152
    const int stride = gridDim.x * blockDim.x;
    for (int i = blockIdx.x * blockDim.x + threadIdx.x; i < n8; i += stride) {
        const f32x4 a = ((const f32x4*)img)[2 * i];
        const f32x4 b = ((const f32x4*)img)[2 * i + 1];
        f16x8 h;
        h[0] = (_Float16)a.x; h[1] = (_Float16)a.y;
        h[2] = (_Float16)a.z; h[3] = (_Float16)a.w;
        h[4] = (_Float16)b.x; h[5] = (_Float16)b.y;
        h[6] = (_Float16)b.z; h[7] = (_Float16)b.w;
        ((f16x8*)img16)[i] = h;
    }
}

// ---------------------------------------------------------------------------
// Pass 1: counting-sort the 3584 (roi,py) items by (source row ay0, roi x)
// so temporally adjacent blocks share image lines (L2 locality). Rewrites
// perm[] entirely every call; within-bin order is atomic-timing dependent
// but harmless (each item writes a disjoint output slice).
// ---------------------------------------------------------------------------
__device__ __forceinline__ int item_key(const int4 roi, int py) {
    const float hf = (float)roi.w;                       // h
    float ysf = ((float)py + 0.5f) * hf / 7.0f - 0.5f;
    ysf = fminf(fmaxf(ysf, 0.0f), hf - 1.0f);
    const int ay0 = roi.y + (int)floorf(ysf);            // [0,127]
    return (ay0 << 6) + roi.x;                           // x in [0,64)
}

__global__ __launch_bounds__(1024) void build_perm_kernel(
    const int* __restrict__ rois, int* __restrict__ perm)
{
    __shared__ int hist[NBINS];      // 32 KB
    __shared__ int wtot[16];
    __shared__ int wbase[16];
    const int tid  = threadIdx.x;
    const int lane = tid & 63;
    const int wid  = tid >> 6;

    #pragma unroll
    for (int i = tid; i < NBINS; i += 1024) hist[i] = 0;
    __syncthreads();

    for (int i = tid; i < NITEMS; i += 1024) {
        const int r = i / POOL, py = i - r * POOL;
        const int4 roi = ((const int4*)rois)[r];
        atomicAdd(&hist[item_key(roi, py)], 1);
    }
    __syncthreads();

    // Exclusive scan of 8192 bins: each thread owns 8 consecutive bins.
    int loc[8];
    int s = 0;
    #pragma unroll
    for (int j = 0; j < 8; ++j) {
        loc[j] = s;
        s += hist[8 * tid + j];
    }
    int inc = s;
    #pragma unroll
    for (int off = 1; off < 64; off <<= 1) {
        const int u = __shfl_up(inc, off, 64);
        if (lane >= off) inc += u;
    }
    if (lane == 63) wtot[wid] = inc;
    __syncthreads();
    if (wid == 0 && lane < 16) {
        int v = wtot[lane];
        int winc = v;
        #pragma unroll
        for (int off = 1; off < 16; off <<= 1) {
            const int u = __shfl_up(winc, off, 16);
            if (lane >= off) winc += u;
        }
        wbase[lane] = winc - v;
    }
    __syncthreads();
    const int texcl = wbase[wid] + inc - s;
    #pragma unroll
    for (int j = 0; j < 8; ++j)
        hist[8 * tid + j] = texcl + loc[j];   // scatter cursors
    __syncthreads();

    for (int i = tid; i < NITEMS; i += 1024) {
        const int r = i / POOL, py = i - r * POOL;
        const int4 roi = ((const int4*)rois)[r];
        const int pos = atomicAdd(&hist[item_key(roi, py)], 1);
        perm[pos] = i;
    }
}

// ---------------------------------------------------------------------------
// Pass 2: gather+blend from the fp16 image. TWO (roi,py) items per
// 256-thread block; 128 threads per item, each owning 8 channels.
// Per thread: 28 x 16B f16x8 loads + 14 x 16B f32x4 NT stores.
// VMEM instr count 301K (was 530K); read bytes 200MB (was 400MB).
// ---------------------------------------------------------------------------
__device__ __forceinline__ void cvt8(const f16x8 v, f32x4& lo, f32x4& hi) {
    lo.x = (float)v[0]; lo.y = (float)v[1]; lo.z = (float)v[2]; lo.w = (float)v[3];
    hi.x = (float)v[4]; hi.y = (float)v[5]; hi.z = (float)v[6]; hi.w = (float)v[7];
}

__global__ __launch_bounds__(256) void roi_pool_gather16_kernel(
    const _Float16* __restrict__ img16,  // (H, W, C) fp16
    const int*      __restrict__ rois,   // (R, 4) as (x, y, w, h)
    const int*      __restrict__ perm,   // (NITEMS) sorted work ids
    float*          __restrict__ out)    // (R, P, P, C) fp32
{
    const int bid = blockIdx.x;                         // 0..1791
    const int sub = threadIdx.x >> 7;                   // 0 or 1
    const int c   = threadIdx.x & 127;                  // channel-octet id
    const int s   = (bid & 7) * (NITEMS / 8) + ((bid >> 3) << 1) + sub;
    const int item = perm[s];
    const int r    = item / POOL;
    const int py   = item - r * POOL;

    const int4 roi = ((const int4*)rois)[r];
    const int x = roi.x, y = roi.y, w = roi.z, h = roi.w;
    const float hf = (float)h, wf = (float)w;

    // y interpolation (same fp32 expression order as reference)
    float ysf = ((float)py + 0.5f) * hf / 7.0f - 0.5f;
    ysf = fminf(fmaxf(ysf, 0.0f), hf - 1.0f);
    const int   y0 = (int)floorf(ysf);
    const int   y1 = min(y0 + 1, h - 1);
    const float fy = ysf - (float)y0;
    const float gy = 1.0f - fy;

    const f16x8* __restrict__ row0 =
        (const f16x8*)img16 + (size_t)(y + y0) * W_IMG * 128;
    const f16x8* __restrict__ row1 =
        (const f16x8*)img16 + (size_t)(y + y1) * W_IMG * 128;

    // x interpolation for all 7 px
    int   ax0[POOL], ax1[POOL];
    float fx[POOL];
    #pragma unroll
    for (int px = 0; px < POOL; ++px) {
        float xsf = ((float)px + 0.5f) * wf / 7.0f - 0.5f;
        xsf = fminf(fmaxf(xsf, 0.0f), wf - 1.0f);
        const int x0 = (int)floorf(xsf);
        const int x1 = min(x0 + 1, w - 1);
        fx[px]  = xsf - (float)x0;
        ax0[px] = x + x0;
        ax1[px] = x + x1;
    }

    f16x8 A[POOL], B[POOL], C_[POOL], D[POOL];
    #pragma unroll
    for (int px = 0; px < POOL; ++px) {
        A[px]  = row0[(ax0[px] << 7) + c];
        B[px]  = row0[(ax1[px] << 7) + c];
    }
    #pragma unroll
    for (int px = 0; px < POOL; ++px) {
        C_[px] = row1[(ax0[px] << 7) + c];
        D[px]  = row1[(ax1[px] << 7) + c];
    }

    f32x4* __restrict__ po =
        (f32x4*)(out + ((size_t)(r * 49 + py * 7)) * C_IMG);

    #pragma unroll
    for (int px = 0; px < POOL; ++px) {
        const float f = fx[px], g = 1.0f - f;
        f32x4 alo, ahi, blo, bhi, clo, chi, dlo, dhi;
        cvt8(A[px],  alo, ahi);
        cvt8(B[px],  blo, bhi);
        cvt8(C_[px], clo, chi);
        cvt8(D[px],  dlo, dhi);
        const f32x4 tlo = alo * g + blo * f;
        const f32x4 thi = ahi * g + bhi * f;
        const f32x4 ulo = clo * g + dlo * f;
        const f32x4 uhi = chi * g + dhi * f;
        const f32x4 olo = tlo * gy + ulo * fy;
        const f32x4 ohi = thi * gy + uhi * fy;
        __builtin_nontemporal_store(olo, &po[(px << 8) + (c << 1)]);
        __builtin_nontemporal_store(ohi, &po[(px << 8) + (c << 1) + 1]);
    }
}

extern "C" void kernel_launch(void* const* d_in, const int* in_sizes, int n_in,
                              void* d_out, int out_size, void* d_ws, size_t ws_size,
                              hipStream_t stream) {
    const float* img  = (const float*)d_in[0];   // (1,128,128,1024) fp32
    const int*   rois = (const int*)d_in[1];     // (1,512,4) int32
    float*       out  = (float*)d_out;           // (1,512,7,7,1024) fp32

    _Float16* img16 = (_Float16*)d_ws;                       // 33.5 MB
    int*      perm  = (int*)((char*)d_ws + IMG16_BYTES);     // +14 KB

    convert_kernel<<<2048, 256, 0, stream>>>(img, img16);
    build_perm_kernel<<<1, 1024, 0, stream>>>(rois, perm);
    roi_pool_gather16_kernel<<<NITEMS / 2, 256, 0, stream>>>(img16, rois, perm, out);
}

// Round 11
// 38.127 us; speedup vs baseline: 1.6998x; 1.6998x over previous
//
#include <hip/hip_runtime.h>

#define POOL 7
#define NUM_ROIS 512
#define H_IMG 128
#define W_IMG 128
#define C_IMG 1024
#define NITEMS (NUM_ROIS * POOL)   // 3584 work items = (roi, py) rows

typedef float f32x4 __attribute__((ext_vector_type(4)));

// ---------------------------------------------------------------------------
// Pre-pass: counting-sort the 3584 (roi,py) work items by source image row
// ay0 = y + y0 (128 bins, parallel Hillis-Steele scan). Rewrites perm[]
// entirely every call; within-bin order is atomic-timing dependent but
// harmless (each item writes a disjoint output slice).
// ---------------------------------------------------------------------------
__device__ __forceinline__ int item_key(const int4 roi, int py) {
    const float hf = (float)roi.w;                       // h
    float ysf = ((float)py + 0.5f) * hf / 7.0f - 0.5f;
    ysf = fminf(fmaxf(ysf, 0.0f), hf - 1.0f);
    return roi.y + (int)floorf(ysf);                     // ay0 in [0,127]
}

__global__ __launch_bounds__(1024) void build_perm_kernel(
    const int* __restrict__ rois, int* __restrict__ perm)
{
    __shared__ int hist[128];
    __shared__ int scan[128];
    const int tid = threadIdx.x;
    if (tid < 128) hist[tid] = 0;
    __syncthreads();

    for (int i = tid; i < NITEMS; i += 1024) {
        const int r = i / POOL, py = i - r * POOL;
        const int4 roi = ((const int4*)rois)[r];
        atomicAdd(&hist[item_key(roi, py)], 1);
    }
    __syncthreads();

    if (tid < 128) scan[tid] = hist[tid];
    __syncthreads();
    #pragma unroll
    for (int off = 1; off < 128; off <<= 1) {
        int v = 0;
        if (tid < 128 && tid >= off) v = scan[tid - off];
        __syncthreads();
        if (tid < 128) scan[tid] += v;
        __syncthreads();
    }
    if (tid < 128) hist[tid] = scan[tid] - hist[tid];   // exclusive cursor
    __syncthreads();

    for (int i = tid; i < NITEMS; i += 1024) {
        const int r = i / POOL, py = i - r * POOL;
        const int4 roi = ((const int4*)rois)[r];
        const int pos = atomicAdd(&hist[item_key(roi, py)], 1);
        perm[pos] = i;
    }
}

// ---------------------------------------------------------------------------
// Main kernel: one 256-thread block per (roi, py) output row, work order
// from perm so each XCD streams a contiguous y-slice. Best-measured config
// (round 5, 37.8us): fp32 gather, 28-load batches, NT stores.
// ---------------------------------------------------------------------------
__global__ __launch_bounds__(256) void roi_pool_row_kernel(
    const float* __restrict__ img,   // (H, W, C)
    const int*   __restrict__ rois,  // (R, 4) as (x, y, w, h)
    const int*   __restrict__ perm,  // (NITEMS) sorted work ids
    float*       __restrict__ out)   // (R, P, P, C)
{
    const int bid  = blockIdx.x;
    const int swz  = (bid & 7) * (NITEMS / 8) + (bid >> 3);
    const int item = perm[swz];
    const int r    = item / POOL;
    const int py   = item - r * POOL;

    const int4 roi = ((const int4*)rois)[r];
    const int x = roi.x, y = roi.y, w = roi.z, h = roi.w;
    const float hf = (float)h, wf = (float)w;

    // y interpolation (same fp32 expression order as reference)
    float ysf = ((float)py + 0.5f) * hf / 7.0f - 0.5f;
    ysf = fminf(fmaxf(ysf, 0.0f), hf - 1.0f);
    const int   y0 = (int)floorf(ysf);
    const int   y1 = min(y0 + 1, h - 1);
    const float fy = ysf - (float)y0;
    const float gy = 1.0f - fy;

    const f32x4* __restrict__ row0 =
        (const f32x4*)(img + (size_t)(y + y0) * W_IMG * C_IMG);
    const f32x4* __restrict__ row1 =
        (const f32x4*)(img + (size_t)(y + y1) * W_IMG * C_IMG);

    // x interpolation for all 7 px
    int   ax0[POOL], ax1[POOL];
    float fx[POOL];
    #pragma unroll
    for (int px = 0; px < POOL; ++px) {
        float xsf = ((float)px + 0.5f) * wf / 7.0f - 0.5f;
        xsf = fminf(fmaxf(xsf, 0.0f), wf - 1.0f);
        const int x0 = (int)floorf(xsf);
        const int x1 = min(x0 + 1, w - 1);
        fx[px]  = xsf - (float)x0;
        ax0[px] = x + x0;
        ax1[px] = x + x1;
    }

    const int t = threadIdx.x;   // 0..255 ; C/4 == 256 exactly

    f32x4 A[POOL], B[POOL], C_[POOL], D[POOL];
    #pragma unroll
    for (int px = 0; px < POOL; ++px) {
        A[px]  = row0[(ax0[px] << 8) + t];
        B[px]  = row0[(ax1[px] << 8) + t];
    }
    #pragma unroll
    for (int px = 0; px < POOL; ++px) {
        C_[px] = row1[(ax0[px] << 8) + t];
        D[px]  = row1[(ax1[px] << 8) + t];
    }

    f32x4* __restrict__ po =
        (f32x4*)(out + ((size_t)(r * 49 + py * 7)) * C_IMG);

    #pragma unroll
    for (int px = 0; px < POOL; ++px) {
        const float f = fx[px], g = 1.0f - f;
        f32x4 top = A[px]  * g + B[px] * f;
        f32x4 bot = C_[px] * g + D[px] * f;
        f32x4 o   = top * gy + bot * fy;
        // Output is write-once, never re-read: bypass cache allocation.
        __builtin_nontemporal_store(o, &po[(px << 8) + t]);
    }
}

extern "C" void kernel_launch(void* const* d_in, const int* in_sizes, int n_in,
                              void* d_out, int out_size, void* d_ws, size_t ws_size,
                              hipStream_t stream) {
    const float* img  = (const float*)d_in[0];   // (1,128,128,1024) fp32
    const int*   rois = (const int*)d_in[1];     // (1,512,4) int32
    float*       out  = (float*)d_out;           // (1,512,7,7,1024) fp32
    int*         perm = (int*)d_ws;              // NITEMS ints of scratch

    build_perm_kernel<<<1, 1024, 0, stream>>>(rois, perm);
    roi_pool_row_kernel<<<NITEMS, 256, 0, stream>>>(img, rois, perm, out);
}